// Round 1
// baseline (91.433 us; speedup 1.0000x reference)
//
#include <hip/hip_runtime.h>
#include <cfloat>

// Problem constants (match reference setup_inputs)
#define BB 4
#define NQ 8192
#define NK 2048
#define CC 128
#define C4 (CC / 4)            // 32 float4 per feature row

#define QPB 128                // queries per block (2 per lane)
#define SPLITS 16              // key splits, one wave each (wave-uniform)
#define KPS (NK / SPLITS)      // 128 keys per split (local idx fits 7 bits)
#define NTHR 1024              // 16 waves

// ---------------------------------------------------------------------------
// Fused: kNN (branchless packed top-4 per split via v_med3, fp64 refine)
//        + inverse-distance-weighted interpolation
//   grid = (NQ/QPB, BB) = (64,4) = 256 blocks -> exactly 1 block/CU
//   QPT=2: each lane scans keys for TWO queries, halving the wave-uniform
//   ds_read_b128 broadcast count per pair (the round-4 bottleneck theory:
//   phase-1 is LDS-issue-bound at ~1 broadcast per 64 pairs; now 1 per 128).
// ---------------------------------------------------------------------------
__global__ __launch_bounds__(NTHR, 4) void fp_fused(
    const float*  __restrict__ xyz_q,
    const float*  __restrict__ xyz_k,
    const float4* __restrict__ vk,
    float4*       __restrict__ out)
{
    __shared__ float4 ks[NK];                          // 32 KiB: {x,y,z,0}
    // packed fp64 candidates: (bits(dd) & ~0x7FF) | global_kidx (11 bits)
    // layout [split][cand][query] -> phase-2b reads are lane-contiguous b64
    __shared__ unsigned long long rd[SPLITS][4][QPB];  // 64 KiB
    __shared__ float sw[QPB][4];                       // 2 KiB
    __shared__ int   si[QPB][4];                       // 2 KiB

    const int b     = blockIdx.y;
    const int qbase = blockIdx.x * QPB;
    const int tid   = threadIdx.x;
    const int lane  = tid & 63;                  // lane within wave
    const int split = tid >> 6;                  // wave id == key split (uniform)

    // ---- stage this batch's keys into LDS (coalesced, 2 keys/thread) ----
    {
        const float* kb = xyz_k + (size_t)b * NK * 3;
        #pragma unroll
        for (int i = tid; i < NK; i += NTHR) {
            ks[i] = make_float4(kb[i * 3 + 0], kb[i * 3 + 1], kb[i * 3 + 2], 0.0f);
        }
    }

    // two queries per lane: q0 = qbase+lane, q1 = qbase+64+lane
    const int q0 = qbase + lane;
    const int q1 = q0 + 64;
    const float ax = xyz_q[(b * NQ + q0) * 3 + 0];
    const float ay = xyz_q[(b * NQ + q0) * 3 + 1];
    const float az = xyz_q[(b * NQ + q0) * 3 + 2];
    const float bx = xyz_q[(b * NQ + q1) * 3 + 0];
    const float by = xyz_q[(b * NQ + q1) * 3 + 1];
    const float bz = xyz_q[(b * NQ + q1) * 3 + 2];

    __syncthreads();

    // wave-uniform key range
    const int kbeg = __builtin_amdgcn_readfirstlane(split * KPS);

    // ---- phase 1: branchless fp32 scan, packed top-4 via med3 insert ----
    // invariant per query: u0 <= u1 <= u2 <= u3 (low 7 bits = local idx)
    float a0 = FLT_MAX, a1 = FLT_MAX, a2 = FLT_MAX, a3 = FLT_MAX;   // q0
    float c0 = FLT_MAX, c1 = FLT_MAX, c2 = FLT_MAX, c3 = FLT_MAX;   // q1

    #pragma unroll 8
    for (int j = 0; j < KPS; ++j) {
        float4 kk = ks[kbeg + j];                // uniform addr -> LDS broadcast
        // query 0
        {
            float dx = ax - kk.x, dy = ay - kk.y, dz = az - kk.z;
            float t = fmaf(dx, dx, fmaf(dy, dy, dz * dz));
            float p = __uint_as_float((__float_as_uint(t) & 0xFFFFFF80u) | (unsigned)j);
            a3 = __builtin_amdgcn_fmed3f(p, a2, a3);
            a2 = __builtin_amdgcn_fmed3f(p, a1, a2);
            a1 = __builtin_amdgcn_fmed3f(p, a0, a1);
            a0 = fminf(a0, p);
        }
        // query 1
        {
            float dx = bx - kk.x, dy = by - kk.y, dz = bz - kk.z;
            float t = fmaf(dx, dx, fmaf(dy, dy, dz * dz));
            float p = __uint_as_float((__float_as_uint(t) & 0xFFFFFF80u) | (unsigned)j);
            c3 = __builtin_amdgcn_fmed3f(p, c2, c3);
            c2 = __builtin_amdgcn_fmed3f(p, c1, c2);
            c1 = __builtin_amdgcn_fmed3f(p, c0, c1);
            c0 = fminf(c0, p);
        }
    }

    // ---- phase 2a: every thread fp64-refines its 2x4 candidates ----
    {
        float ua[4] = { a0, a1, a2, a3 };
        float ub[4] = { c0, c1, c2, c3 };
        #pragma unroll
        for (int c = 0; c < 4; ++c) {
            {
                int kidx = kbeg + (int)(__float_as_uint(ua[c]) & 0x7Fu);
                float4 ka = ks[kidx];
                double dx = (double)ax - (double)ka.x;
                double dy = (double)ay - (double)ka.y;
                double dz = (double)az - (double)ka.z;
                double dd = dx * dx + dy * dy + dz * dz;
                rd[split][c][lane] =
                    (((unsigned long long)__double_as_longlong(dd)) & ~0x7FFull)
                    | (unsigned long long)kidx;
            }
            {
                int kidx = kbeg + (int)(__float_as_uint(ub[c]) & 0x7Fu);
                float4 ka = ks[kidx];
                double dx = (double)bx - (double)ka.x;
                double dy = (double)by - (double)ka.y;
                double dz = (double)bz - (double)ka.z;
                double dd = dx * dx + dy * dy + dz * dz;
                rd[split][c][lane + 64] =
                    (((unsigned long long)__double_as_longlong(dd)) & ~0x7FFull)
                    | (unsigned long long)kidx;
            }
        }
    }
    __syncthreads();

    // ---- phase 2b: 2 waves select exact top-3 of 64 candidates per query ----
    if (tid < QPB) {
        // packed uint64s reinterpreted as positive doubles stay order-correct
        double m0 = DBL_MAX, m1 = DBL_MAX, m2 = DBL_MAX;
        #pragma unroll 4
        for (int s = 0; s < SPLITS; ++s) {
            #pragma unroll
            for (int c = 0; c < 4; ++c) {
                double x = __longlong_as_double((long long)rd[s][c][tid]);
                double t1 = fmax(x, m1), t0 = fmax(x, m0);
                m2 = fmin(m2, t1);
                m1 = fmin(m1, t0);
                m0 = fmin(m0, x);
            }
        }
        unsigned long long b0 = (unsigned long long)__double_as_longlong(m0);
        unsigned long long b1 = (unsigned long long)__double_as_longlong(m1);
        unsigned long long b2 = (unsigned long long)__double_as_longlong(m2);
        double e0 = __longlong_as_double((long long)(b0 & ~0x7FFull));
        double e1 = __longlong_as_double((long long)(b1 & ~0x7FFull));
        double e2 = __longlong_as_double((long long)(b2 & ~0x7FFull));
        e0 = fmax(e0, 1e-10);
        e1 = fmax(e1, 1e-10);
        e2 = fmax(e2, 1e-10);
        double w0 = 1.0 / e0, w1 = 1.0 / e1, w2 = 1.0 / e2;
        double s  = w0 + w1 + w2;
        sw[tid][0] = (float)(w0 / s);
        sw[tid][1] = (float)(w1 / s);
        sw[tid][2] = (float)(w2 / s);
        si[tid][0] = (int)(b0 & 0x7FFull);
        si[tid][1] = (int)(b1 & 0x7FFull);
        si[tid][2] = (int)(b2 & 0x7FFull);
    }
    __syncthreads();

    // ---- phase 3: gather + weighted sum, coalesced float4 writes ----
    const float4* vb = vk + (size_t)b * NK * C4;
    float4* ob = out + ((size_t)b * NQ + qbase) * C4;
    #pragma unroll
    for (int r = 0; r < (QPB * C4) / NTHR; ++r) {   // 4 iters
        int o  = r * NTHR + tid;
        int qq = o >> 5;          // C4 = 32 float4 per query
        int c4 = o & (C4 - 1);
        float w0 = sw[qq][0], w1 = sw[qq][1], w2 = sw[qq][2];
        int   j0 = si[qq][0], j1 = si[qq][1], j2 = si[qq][2];
        float4 v0 = vb[j0 * C4 + c4];
        float4 v1 = vb[j1 * C4 + c4];
        float4 v2 = vb[j2 * C4 + c4];
        float4 res;
        res.x = fmaf(w0, v0.x, fmaf(w1, v1.x, w2 * v2.x));
        res.y = fmaf(w0, v0.y, fmaf(w1, v1.y, w2 * v2.y));
        res.z = fmaf(w0, v0.z, fmaf(w1, v1.z, w2 * v2.z));
        res.w = fmaf(w0, v0.w, fmaf(w1, v1.w, w2 * v2.w));
        ob[o] = res;
    }
}

// ---------------------------------------------------------------------------
extern "C" void kernel_launch(void* const* d_in, const int* in_sizes, int n_in,
                              void* d_out, int out_size, void* d_ws, size_t ws_size,
                              hipStream_t stream)
{
    const float* xyz_q = (const float*)d_in[0];
    const float* xyz_k = (const float*)d_in[1];
    const float* v_k   = (const float*)d_in[2];

    fp_fused<<<dim3(NQ / QPB, BB), dim3(NTHR), 0, stream>>>(
        xyz_q, xyz_k, (const float4*)v_k, (float4*)d_out);
}

// Round 2
// 88.336 us; speedup vs baseline: 1.0351x; 1.0351x over previous
//
#include <hip/hip_runtime.h>
#include <cfloat>

// Problem constants (match reference setup_inputs)
#define BB 4
#define NQ 8192
#define NK 2048
#define CC 128
#define C4 (CC / 4)            // 32 float4 per feature row

#define QPB 64                 // queries per block (= lane id)
#define SPLITS 16              // key splits, one wave each (wave-uniform)
#define KPS (NK / SPLITS)      // 128 keys per split (local idx fits 7 bits)
#define NTHR (QPB * SPLITS)    // 1024 threads per block

// ---------------------------------------------------------------------------
// Fused: kNN (branchless packed top-4 per split via v_med3) + IDW interp.
//   grid = (NQ/QPB, BB) = (128,4) = 512 blocks -> 2 blocks/CU = 32 waves/CU
//   Round-2 changes vs the 43us round-0 kernel:
//     * expansion-form distance (|k|^2 staged in ks.w, -2q in regs):
//       9 VALU/pair instead of 11
//     * phase 2a stores packed fp32 candidates (16 KiB rd, no fp64, no
//       LDS gathers); exactness restored in phase 2b by cvt-to-fp64 +
//       idx-in-low-bits top-4, then fp64 refine of just those 4.
// ---------------------------------------------------------------------------
__global__ __launch_bounds__(NTHR, 8) void fp_fused(
    const float*  __restrict__ xyz_q,
    const float*  __restrict__ xyz_k,
    const float4* __restrict__ vk,
    float4*       __restrict__ out)
{
    __shared__ float4 ks[NK];                 // 32 KiB: {x,y,z,|k|^2}
    __shared__ unsigned rd[SPLITS][4][QPB];   // 16 KiB: packed fp32 cands
    __shared__ float sw[QPB][4];              // 1 KiB
    __shared__ int   si[QPB][4];              // 1 KiB

    const int b     = blockIdx.y;
    const int qbase = blockIdx.x * QPB;
    const int tid   = threadIdx.x;
    const int lane  = tid & 63;               // query within block
    const int split = tid >> 6;               // wave id == key split (uniform)
    const int q     = qbase + lane;

    // ---- stage keys into LDS with |k|^2 in .w (coalesced, 2 keys/thread) --
    {
        const float* kb = xyz_k + (size_t)b * NK * 3;
        #pragma unroll
        for (int i = tid; i < NK; i += NTHR) {
            float x = kb[i * 3 + 0], y = kb[i * 3 + 1], z = kb[i * 3 + 2];
            ks[i] = make_float4(x, y, z, fmaf(x, x, fmaf(y, y, z * z)));
        }
    }

    const float qx = xyz_q[(b * NQ + q) * 3 + 0];
    const float qy = xyz_q[(b * NQ + q) * 3 + 1];
    const float qz = xyz_q[(b * NQ + q) * 3 + 2];
    const float m2x = -2.0f * qx, m2y = -2.0f * qy, m2z = -2.0f * qz;
    const float qq2 = fmaf(qx, qx, fmaf(qy, qy, qz * qz));

    __syncthreads();

    // wave-uniform key range
    const int kbeg = __builtin_amdgcn_readfirstlane(split * KPS);

    // ---- phase 1: branchless fp32 scan, packed top-4 via med3 insert ----
    // t = |q|^2 + |k|^2 - 2 q.k  (same form as reference; >= -eps)
    // invariant: u0 <= u1 <= u2 <= u3, low 7 bits = local key index
    float u0 = FLT_MAX, u1 = FLT_MAX, u2 = FLT_MAX, u3 = FLT_MAX;

    #pragma unroll 8
    for (int j = 0; j < KPS; ++j) {
        float4 kk = ks[kbeg + j];             // uniform addr -> LDS broadcast
        float t = fmaf(kk.x, m2x,
                  fmaf(kk.y, m2y,
                  fmaf(kk.z, m2z, kk.w + qq2)));
        float p = __uint_as_float((__float_as_uint(t) & 0xFFFFFF80u) | (unsigned)j);
        u3 = __builtin_amdgcn_fmed3f(p, u2, u3);
        u2 = __builtin_amdgcn_fmed3f(p, u1, u2);
        u1 = __builtin_amdgcn_fmed3f(p, u0, u1);
        u0 = fminf(u0, p);
    }

    // ---- phase 2a: store packed fp32 candidates (lane-contiguous b32) ----
    rd[split][0][lane] = __float_as_uint(u0);
    rd[split][1][lane] = __float_as_uint(u1);
    rd[split][2][lane] = __float_as_uint(u2);
    rd[split][3][lane] = __float_as_uint(u3);
    __syncthreads();

    // ---- phase 2b: wave 0 selects global top-4, refines in fp64, picks 3 --
    if (tid < QPB) {
        // convert packed fp32 -> fp64 with 11-bit global idx in low bits
        // (cvt_f64_f32 leaves low 29 mantissa bits zero); float order preserved
        double m0 = DBL_MAX, m1 = DBL_MAX, m2 = DBL_MAX, m3 = DBL_MAX;
        #pragma unroll 4
        for (int s = 0; s < SPLITS; ++s) {
            #pragma unroll
            for (int c = 0; c < 4; ++c) {
                unsigned pb = rd[s][c][tid];
                float vf = __uint_as_float(pb & 0xFFFFFF80u);
                unsigned long long gidx =
                    (unsigned long long)(s * KPS) + (pb & 0x7Fu);
                unsigned long long xb =
                    (unsigned long long)__double_as_longlong((double)vf) | gidx;
                double x = __longlong_as_double((long long)xb);
                m3 = fmin(m3, fmax(x, m2));
                m2 = fmin(m2, fmax(x, m1));
                m1 = fmin(m1, fmax(x, m0));
                m0 = fmin(m0, x);
            }
        }

        // fp64-exact refine of the 4 survivors
        double d0, d1, d2, d3;
        int    i0, i1, i2, i3;
        {
            unsigned long long mb[4] = {
                (unsigned long long)__double_as_longlong(m0),
                (unsigned long long)__double_as_longlong(m1),
                (unsigned long long)__double_as_longlong(m2),
                (unsigned long long)__double_as_longlong(m3)
            };
            double dd[4]; int ii[4];
            #pragma unroll
            for (int c = 0; c < 4; ++c) {
                int kidx = (int)(mb[c] & 0x7FFull);
                float4 ka = ks[kidx];
                double dx = (double)qx - (double)ka.x;
                double dy = (double)qy - (double)ka.y;
                double dz = (double)qz - (double)ka.z;
                dd[c] = dx * dx + dy * dy + dz * dz;   // exact for fp32 inputs
                ii[c] = kidx;
            }
            d0 = dd[0]; d1 = dd[1]; d2 = dd[2]; d3 = dd[3];
            i0 = ii[0]; i1 = ii[1]; i2 = ii[2]; i3 = ii[3];
        }

        // sort-4 network (ascending), keep smallest 3
        #define CSW(da, db, ia, ib)                                     \
            { bool c_ = (da) > (db);                                    \
              double dt_ = c_ ? (db) : (da); (db) = c_ ? (da) : (db);   \
              (da) = dt_;                                               \
              int it_ = c_ ? (ib) : (ia); (ib) = c_ ? (ia) : (ib);      \
              (ia) = it_; }
        CSW(d0, d1, i0, i1);
        CSW(d2, d3, i2, i3);
        CSW(d0, d2, i0, i2);
        CSW(d1, d3, i1, i3);
        CSW(d1, d2, i1, i2);
        #undef CSW

        double e0 = fmax(d0, 1e-10);
        double e1 = fmax(d1, 1e-10);
        double e2 = fmax(d2, 1e-10);
        double w0 = 1.0 / e0, w1 = 1.0 / e1, w2 = 1.0 / e2;
        double s  = w0 + w1 + w2;
        sw[tid][0] = (float)(w0 / s);
        sw[tid][1] = (float)(w1 / s);
        sw[tid][2] = (float)(w2 / s);
        si[tid][0] = i0;
        si[tid][1] = i1;
        si[tid][2] = i2;
    }
    __syncthreads();

    // ---- phase 3: gather + weighted sum, coalesced float4 writes ----
    const float4* vb = vk + (size_t)b * NK * C4;
    float4* ob = out + ((size_t)b * NQ + qbase) * C4;
    #pragma unroll
    for (int r = 0; r < (QPB * C4) / NTHR; ++r) {   // 2 iters
        int o  = r * NTHR + tid;
        int qq = o >> 5;          // C4 = 32 float4 per query
        int c4 = o & (C4 - 1);
        float w0 = sw[qq][0], w1 = sw[qq][1], w2 = sw[qq][2];
        int   j0 = si[qq][0], j1 = si[qq][1], j2 = si[qq][2];
        float4 v0 = vb[j0 * C4 + c4];
        float4 v1 = vb[j1 * C4 + c4];
        float4 v2 = vb[j2 * C4 + c4];
        float4 res;
        res.x = fmaf(w0, v0.x, fmaf(w1, v1.x, w2 * v2.x));
        res.y = fmaf(w0, v0.y, fmaf(w1, v1.y, w2 * v2.y));
        res.z = fmaf(w0, v0.z, fmaf(w1, v1.z, w2 * v2.z));
        res.w = fmaf(w0, v0.w, fmaf(w1, v1.w, w2 * v2.w));
        ob[o] = res;
    }
}

// ---------------------------------------------------------------------------
extern "C" void kernel_launch(void* const* d_in, const int* in_sizes, int n_in,
                              void* d_out, int out_size, void* d_ws, size_t ws_size,
                              hipStream_t stream)
{
    const float* xyz_q = (const float*)d_in[0];
    const float* xyz_k = (const float*)d_in[1];
    const float* v_k   = (const float*)d_in[2];

    fp_fused<<<dim3(NQ / QPB, BB), dim3(NTHR), 0, stream>>>(
        xyz_q, xyz_k, (const float4*)v_k, (float4*)d_out);
}